// Round 6
// baseline (184.513 us; speedup 1.0000x reference)
//
#include <hip/hip_runtime.h>

#define BATCH 4096
#define SEQT  512
#define HID   32
#define CH    16                    // timestep chunk held in LDS history
#define RS    20                    // dwords per t-row (80 B, 16B-aligned, 2-way banks on b128 readback)
#define SEQSTR (CH * RS + 16)       // 336 dwords; %32==16 -> seq halves split the bank space

typedef _Float16 f16;
typedef _Float16 h2 __attribute__((ext_vector_type(2)));

#if __has_builtin(__builtin_amdgcn_fdot2)
#define FDOT2(a, b, c) __builtin_amdgcn_fdot2((a), (b), (c), false)
#else
#define FDOT2(a, b, c) fmaf((float)(a)[1], (float)(b)[1], fmaf((float)(a)[0], (float)(b)[0], (c)))
#endif

#if __has_builtin(__builtin_amdgcn_exp2f)
#define FAST_EXP2(x) __builtin_amdgcn_exp2f(x)
#else
#define FAST_EXP2(x) exp2f(x)
#endif
#if __has_builtin(__builtin_amdgcn_rcpf)
#define FAST_RCP(x) __builtin_amdgcn_rcpf(x)
#else
#define FAST_RCP(x) (1.0f / (x))
#endif

// rotate-by-i within each 16-lane row; direction-proof (weight indices are
// derived through the SAME primitive).
#if __has_builtin(__builtin_amdgcn_update_dpp)
#define ROT16(v, i) __builtin_amdgcn_update_dpp(0, (v), 0x120 + (i), 0xF, 0xF, true)
#else
#define ROT16(v, i) __shfl((v), (int)((threadIdx.x & ~15u) | ((threadIdx.x + (i)) & 15u)), 64)
#endif

#define GATHER15(dst, src) \
    dst[1]  = ROT16(src, 1);  dst[2]  = ROT16(src, 2);  dst[3]  = ROT16(src, 3);  \
    dst[4]  = ROT16(src, 4);  dst[5]  = ROT16(src, 5);  dst[6]  = ROT16(src, 6);  \
    dst[7]  = ROT16(src, 7);  dst[8]  = ROT16(src, 8);  dst[9]  = ROT16(src, 9);  \
    dst[10] = ROT16(src, 10); dst[11] = ROT16(src, 11); dst[12] = ROT16(src, 12); \
    dst[13] = ROT16(src, 13); dst[14] = ROT16(src, 14); dst[15] = ROT16(src, 15);

// lane exchange j <-> j^16 within each 32-lane half (BitMode xor=16)
#if __has_builtin(__builtin_amdgcn_ds_swizzle)
#define XOR16(v) __builtin_amdgcn_ds_swizzle((v), 0x401F)
#else
#define XOR16(v) __shfl_xor((v), 16, 64)
#endif

#define BCI(x) __builtin_bit_cast(h2, (x))
#define BCF(x) __builtin_bit_cast(h2, (x))

static __device__ __forceinline__ int packh(float a, float b) {
#if __has_builtin(__builtin_amdgcn_cvt_pkrtz)
    return __builtin_bit_cast(int, __builtin_amdgcn_cvt_pkrtz(a, b));
#else
    h2 v = {(f16)a, (f16)b};
    return __builtin_bit_cast(int, v);
#endif
}

// One wave = 2 sequences (one per 32-lane half); lane j (=lane&31) owns h[j].
// 2048 waves -> 2 waves/SIMD: per-wave issue is low AND stalls overlap.
// Recurrence: after tanh, one ds_swizzle(xor16) fetches h[j^16]; the pair is
// packed CANONICALLY (h[l], h[l+16]) so both 16-lane DPP rows hold identical
// dwords; 15 row_ror DPP movs all-gather the full h vector in registers and
// 16 v_dot2_f32_f16 per lane compute the whole k-sum. 2*log2e is pre-folded
// into W_hh/W_ih/biases so exp2 needs no preceding multiply. x comes straight
// from global (float4 per 4 steps, prefetched a group ahead, row-uniform).
// LDS per step: 1 swizzle + 1 conflict-free spill write (output dot deferred
// to a chunk-end pass).
__global__ __launch_bounds__(64) void rnn_kernel(
    const float* __restrict__ x,      // [B, T]
    const float* __restrict__ h0,     // [B, H]
    const float* __restrict__ W_ih,   // [H]
    const float* __restrict__ b_ih,   // [H]
    const float* __restrict__ W_hh,   // [H, H] row-major
    const float* __restrict__ b_hh,   // [H]
    const float* __restrict__ W_out,  // [H]
    const float* __restrict__ b_out,  // [1]
    float* __restrict__ out)          // [B*T] outs, then [B*H] hT
{
    const int lane = threadIdx.x & 63;
    const int g    = lane >> 5;       // sequence-in-wave (0/1)
    const int j    = lane & 31;       // hidden index
    const int l    = lane & 15;       // canonical dword index
    const bool up  = (j & 16) != 0;
    const int bs0  = blockIdx.x * 2;
    const int bseq = bs0 + g;

    __shared__ __align__(16) float hist[2 * SEQSTR];  // 2.7 KB

    // rotation source-index sequence, derived through ROT16 itself
    int idx[16];
    idx[0] = l;
    GATHER15(idx, l);

    const float SC = 2.8853900817779268f;  // 2*log2(e)

    // per-lane recurrent weights, pre-scaled by SC, paired (s, s+16)
    h2 Wr[16];
    #pragma unroll
    for (int i = 0; i < 16; ++i) {
        const int s = idx[i];
        Wr[i] = h2{(f16)(W_hh[j * HID + s] * SC), (f16)(W_hh[j * HID + s + 16] * SC)};
    }
    // output weights paired (k, k+16) -- lane-uniform, rows read in order
    h2 Wo[16];
    #pragma unroll
    for (int i = 0; i < 16; ++i)
        Wo[i] = h2{(f16)W_out[i], (f16)W_out[i + 16]};

    const float wih  = W_ih[j] * SC;
    const float bias = (b_ih[j] + b_hh[j]) * SC;
    const float bout = b_out[0];

    // canonical seed: dword l = (h[l], h[l+16]) in BOTH 16-lane rows
    int d0 = packh(h0[(size_t)bseq * HID + l], h0[(size_t)bseq * HID + l + 16]);

    const float* xg = x + (size_t)bseq * SEQT;   // row-uniform per 32-lane half
    float*       og = out + (size_t)bs0 * SEQT;

    float4 xq = *reinterpret_cast<const float4*>(xg);  // steps 0..3

#define STEP(XC, T2)                                                          \
    {                                                                         \
        int d[16];                                                            \
        d[0] = d0;                                                            \
        GATHER15(d, d0);                                                      \
        float a0 = fmaf((XC), wih, bias);                                     \
        float a1 = FDOT2(BCI(d[1]), Wr[1], 0.0f);                             \
        float a2 = FDOT2(BCI(d[2]), Wr[2], 0.0f);                             \
        float a3 = FDOT2(BCI(d[3]), Wr[3], 0.0f);                             \
        a0 = FDOT2(BCI(d[0]),  Wr[0],  a0);                                   \
        a0 = FDOT2(BCI(d[4]),  Wr[4],  a0);                                   \
        a1 = FDOT2(BCI(d[5]),  Wr[5],  a1);                                   \
        a2 = FDOT2(BCI(d[6]),  Wr[6],  a2);                                   \
        a3 = FDOT2(BCI(d[7]),  Wr[7],  a3);                                   \
        a0 = FDOT2(BCI(d[8]),  Wr[8],  a0);                                   \
        a1 = FDOT2(BCI(d[9]),  Wr[9],  a1);                                   \
        a2 = FDOT2(BCI(d[10]), Wr[10], a2);                                   \
        a3 = FDOT2(BCI(d[11]), Wr[11], a3);                                   \
        a0 = FDOT2(BCI(d[12]), Wr[12], a0);                                   \
        a1 = FDOT2(BCI(d[13]), Wr[13], a1);                                   \
        a2 = FDOT2(BCI(d[14]), Wr[14], a2);                                   \
        a3 = FDOT2(BCI(d[15]), Wr[15], a3);                                   \
        const float p  = (a0 + a1) + (a2 + a3);      /* pre-scaled by SC */   \
        const float e  = FAST_EXP2(p);                                        \
        const float hn = fmaf(-2.0f, FAST_RCP(e + 1.0f), 1.0f);               \
        const float sw = __builtin_bit_cast(float,                            \
                             XOR16(__builtin_bit_cast(int, hn)));             \
        const float lo = up ? sw : hn;   /* h[l]    */                        \
        const float hi = up ? hn : sw;   /* h[l+16] */                        \
        d0 = packh(lo, hi);                                                   \
        hist[g * SEQSTR + (T2) * RS + l] = __builtin_bit_cast(float, d0);     \
        __builtin_amdgcn_wave_barrier();                                      \
    }

    for (int tc = 0; tc < SEQT; tc += CH) {
        #pragma unroll
        for (int tg = 0; tg < CH; tg += 4) {
            int tnext = tc + tg + 4;
            if (tnext > SEQT - 4) tnext = SEQT - 4;
            const float4 xqn = *reinterpret_cast<const float4*>(xg + tnext);
            STEP(xq.x, tg + 0)
            STEP(xq.y, tg + 1)
            STEP(xq.z, tg + 2)
            STEP(xq.w, tg + 3)
            xq = xqn;
        }

        // ---- chunk-end output pass: lanes 0..31 -> (seq, t) ----
        if (lane < 32) {
            const int g2 = lane >> 4;
            const int t  = lane & 15;
            const float4* hp =
                reinterpret_cast<const float4*>(&hist[g2 * SEQSTR + t * RS]);
            const float4 q0 = hp[0], q1 = hp[1], q2 = hp[2], q3 = hp[3];
            float o0 = FDOT2(BCF(q0.x), Wo[0],  bout);
            float o1 = FDOT2(BCF(q0.y), Wo[1],  0.0f);
            float o2 = FDOT2(BCF(q0.z), Wo[2],  0.0f);
            float o3 = FDOT2(BCF(q0.w), Wo[3],  0.0f);
            o0 = FDOT2(BCF(q1.x), Wo[4],  o0);
            o1 = FDOT2(BCF(q1.y), Wo[5],  o1);
            o2 = FDOT2(BCF(q1.z), Wo[6],  o2);
            o3 = FDOT2(BCF(q1.w), Wo[7],  o3);
            o0 = FDOT2(BCF(q2.x), Wo[8],  o0);
            o1 = FDOT2(BCF(q2.y), Wo[9],  o1);
            o2 = FDOT2(BCF(q2.z), Wo[10], o2);
            o3 = FDOT2(BCF(q2.w), Wo[11], o3);
            o0 = FDOT2(BCF(q3.x), Wo[12], o0);
            o1 = FDOT2(BCF(q3.y), Wo[13], o1);
            o2 = FDOT2(BCF(q3.z), Wo[14], o2);
            o3 = FDOT2(BCF(q3.w), Wo[15], o3);
            og[(size_t)g2 * SEQT + tc + t] = (o0 + o1) + (o2 + o3);
        }
        __builtin_amdgcn_wave_barrier();
    }
#undef STEP

    // final hidden state [1, B, H]
    const h2 hf = BCI(d0);
    out[(size_t)BATCH * SEQT + (size_t)bseq * HID + j] = up ? (float)hf[1] : (float)hf[0];
}

extern "C" void kernel_launch(void* const* d_in, const int* in_sizes, int n_in,
                              void* d_out, int out_size, void* d_ws, size_t ws_size,
                              hipStream_t stream) {
    const float* x     = (const float*)d_in[0];
    const float* h0    = (const float*)d_in[1];
    const float* W_ih  = (const float*)d_in[2];
    const float* b_ih  = (const float*)d_in[3];
    const float* W_hh  = (const float*)d_in[4];
    const float* b_hh  = (const float*)d_in[5];
    const float* W_out = (const float*)d_in[6];
    const float* b_out = (const float*)d_in[7];
    float* outp = (float*)d_out;

    dim3 grid(BATCH / 2);   // 2048 waves, 2 sequences each -> 2 waves/SIMD
    dim3 block(64);
    hipLaunchKernelGGL(rnn_kernel, grid, block, 0, stream,
                       x, h0, W_ih, b_ih, W_hh, b_hh, W_out, b_out, outp);
}